// Round 5
// baseline (522.602 us; speedup 1.0000x reference)
//
#include <hip/hip_runtime.h>
#include <math.h>

#define HIDDEN 4096
#define NEXP   128
#define TOPK   8
#define BM     64
#define BKC    64                  // K per chunk (wave does its wk-half: K=32)
#define NCHUNK (HIDDEN / BKC)      // 64
#define SS     132                 // padded stride for score rows in epilogue

typedef __attribute__((ext_vector_type(8))) short short8;  // 8 bf16 (4 VGPR)
typedef __attribute__((ext_vector_type(4))) float f32x4;   // MFMA accumulator

__device__ __forceinline__ unsigned pack2(unsigned a, unsigned b) {
  // low ushort = top16 of a, high ushort = top16 of b
  return (a >> 16) | (b & 0xFFFF0000u);
}

// Triple bf16 split: x = hi + mid + lo + O(2^-24 x). hi/mid round-half-away.
struct Split3 { uint4 h, m, l; };
__device__ __forceinline__ Split3 split8(float4 a, float4 b) {
  float x[8] = {a.x, a.y, a.z, a.w, b.x, b.y, b.z, b.w};
  unsigned h[8], m[8], l[8];
#pragma unroll
  for (int j = 0; j < 8; ++j) {
    unsigned u  = __float_as_uint(x[j]);
    unsigned hb = (u + 0x8000u) & 0xFFFF0000u;
    float rh    = x[j] - __uint_as_float(hb);
    unsigned um = __float_as_uint(rh);
    unsigned mb = (um + 0x8000u) & 0xFFFF0000u;
    float rm    = rh - __uint_as_float(mb);
    h[j] = hb; m[j] = mb; l[j] = __float_as_uint(rm);
  }
  Split3 s;
  s.h = make_uint4(pack2(h[0],h[1]), pack2(h[2],h[3]), pack2(h[4],h[5]), pack2(h[6],h[7]));
  s.m = make_uint4(pack2(m[0],m[1]), pack2(m[2],m[3]), pack2(m[4],m[5]), pack2(m[6],m[7]));
  s.l = make_uint4(pack2(l[0],l[1]), pack2(l[2],l[3]), pack2(l[4],l[5]), pack2(l[6],l[7]));
  return s;
}

// ---- pre-pass: split W (fp32) into 3 bf16 planes, packed in MFMA B-fragment
// order.  fid = et*128 + kc  (et = 16-expert tile, kc = K/32 chunk).
// wp[fid*1536 + s*512 + lane*8 ..] = W_split_s[et*16 + (lane&15)][kc*32 + (lane>>4)*8 ..]
__global__ __launch_bounds__(256) void pack_w_kernel(
    const float* __restrict__ w, ushort* __restrict__ wp)
{
  const int g    = blockIdx.x * 256 + threadIdx.x;  // 65536 threads
  const int lane = g & 63;
  const int fid  = g >> 6;                          // 0..1023
  const int et   = fid >> 7;
  const int kc   = fid & 127;
  const int e    = et * 16 + (lane & 15);
  const int k0   = kc * 32 + (lane >> 4) * 8;
  const float4 x0 = *(const float4*)(w + (size_t)e * HIDDEN + k0);
  const float4 x1 = *(const float4*)(w + (size_t)e * HIDDEN + k0 + 4);
  Split3 s = split8(x0, x1);
  uint4* dst = (uint4*)wp + (size_t)fid * 3 * 64;
  dst[0 * 64 + lane] = s.h;
  dst[1 * 64 + lane] = s.m;
  dst[2 * 64 + lane] = s.l;
}

__global__ __launch_bounds__(512, 2) void router_kernel(
    const float*  __restrict__ h,     // [T, HIDDEN]
    const ushort* __restrict__ wp,    // packed split W (see pack_w_kernel)
    const float*  __restrict__ bias,  // [NEXP]
    float* __restrict__ out,          // [T*8] indices (as float) then [T*8] weights
    int T)
{
  __shared__ float Ss[BM * SS];      // score buffer (epilogue only)
  const int tid  = threadIdx.x;
  const int row0 = blockIdx.x * BM;

  // wave roles: wn = expert-column tile (32 experts), wk = K-parity half
  const int wid  = tid >> 6;
  const int wn   = wid & 3;
  const int wk   = wid >> 2;
  const int lane = tid & 63;
  const int lrow = lane & 15;   // MFMA row/col index within 16
  const int lk   = lane >> 4;   // MFMA k-group (8 contiguous k)

  // Per-lane A pointers: row = row0 + mi*16 + lrow, k = c*64 + wk*32 + lk*8
  const float* pA[4];
#pragma unroll
  for (int mi = 0; mi < 4; ++mi)
    pA[mi] = h + (size_t)(row0 + mi * 16 + lrow) * HIDDEN + wk * 32 + lk * 8;

  // Per-lane B fragment base pointers; chunk stride 3072 ushorts
  const ushort* pB0 = wp + (size_t)((wn * 2 + 0) * 128 + wk) * 1536 + (size_t)lane * 8;
  const ushort* pB1 = wp + (size_t)((wn * 2 + 1) * 128 + wk) * 1536 + (size_t)lane * 8;

  f32x4 acc[4][2];
#pragma unroll
  for (int i = 0; i < 4; ++i)
#pragma unroll
    for (int j = 0; j < 2; ++j) acc[i][j] = (f32x4){0.f, 0.f, 0.f, 0.f};

  // 3-slot B rotation (named slots, static indexing only)
  short8 bf0[2][3], bf1[2][3], bf2[2][3];
  // A raw registers, chunk c (reloaded per-mi for c+1 after consumption)
  float4 ar[4][2];

#define LOAD_B(slot, cidx)                                                \
  {                                                                       \
    const ushort* b0_ = pB0 + (size_t)(cidx) * 3072;                      \
    const ushort* b1_ = pB1 + (size_t)(cidx) * 3072;                      \
    _Pragma("unroll")                                                     \
    for (int s_ = 0; s_ < 3; ++s_) {                                      \
      slot[0][s_] = *(const short8*)(b0_ + s_ * 512);                     \
      slot[1][s_] = *(const short8*)(b1_ + s_ * 512);                     \
    }                                                                     \
  }

  // ---- prologue: A(0) and B(0), B(1) in flight
#pragma unroll
  for (int mi = 0; mi < 4; ++mi) {
    ar[mi][0] = *(const float4*)(pA[mi]);
    ar[mi][1] = *(const float4*)(pA[mi] + 4);
  }
  LOAD_B(bf0, 0)
  LOAD_B(bf1, 1)

  // body: consume A(c)+B(c) (slot), prefetch A(c+1) per-mi and B(c+2) (nslot)
#define BODY(slot, nslot, c, pref)                                        \
  {                                                                       \
    if (pref) { const int cb_ = ((c) + 2 > 63) ? 63 : ((c) + 2);          \
                LOAD_B(nslot, cb_) }                                      \
    __builtin_amdgcn_sched_barrier(0);                                    \
    _Pragma("unroll")                                                     \
    for (int mi = 0; mi < 4; ++mi) {                                      \
      Split3 s_ = split8(ar[mi][0], ar[mi][1]);                           \
      short8 afh = *(short8*)&s_.h;                                       \
      short8 afm = *(short8*)&s_.m;                                       \
      short8 afl = *(short8*)&s_.l;                                       \
      if (pref) {                                                         \
        ar[mi][0] = *(const float4*)(pA[mi] + ((c) + 1) * BKC);           \
        ar[mi][1] = *(const float4*)(pA[mi] + ((c) + 1) * BKC + 4);       \
      }                                                                   \
      __builtin_amdgcn_s_setprio(1);                                      \
      _Pragma("unroll")                                                   \
      for (int ni = 0; ni < 2; ++ni) {                                    \
        f32x4 cc = acc[mi][ni];                                           \
        cc = __builtin_amdgcn_mfma_f32_16x16x32_bf16(afh, slot[ni][0], cc, 0, 0, 0); \
        cc = __builtin_amdgcn_mfma_f32_16x16x32_bf16(afh, slot[ni][1], cc, 0, 0, 0); \
        cc = __builtin_amdgcn_mfma_f32_16x16x32_bf16(afm, slot[ni][0], cc, 0, 0, 0); \
        cc = __builtin_amdgcn_mfma_f32_16x16x32_bf16(afh, slot[ni][2], cc, 0, 0, 0); \
        cc = __builtin_amdgcn_mfma_f32_16x16x32_bf16(afl, slot[ni][0], cc, 0, 0, 0); \
        cc = __builtin_amdgcn_mfma_f32_16x16x32_bf16(afm, slot[ni][1], cc, 0, 0, 0); \
        acc[mi][ni] = cc;                                                 \
      }                                                                   \
      __builtin_amdgcn_s_setprio(0);                                      \
    }                                                                     \
  }

  // main loop: chunks 0..62 in groups of 3 (static slot rotation)
  for (int c3 = 0; c3 < 63; c3 += 3) {
    BODY(bf0, bf2, c3 + 0, true)
    BODY(bf1, bf0, c3 + 1, true)
    BODY(bf2, bf1, c3 + 2, true)
  }
  // tail: chunk 63 (slot 63%3 == 0), no prefetch
  BODY(bf0, bf2, 63, false)

#undef BODY
#undef LOAD_B

  // ---- combine wave-pair K-partials in LDS
  if (wk == 1) {
#pragma unroll
    for (int mi = 0; mi < 4; ++mi)
#pragma unroll
      for (int ni = 0; ni < 2; ++ni)
#pragma unroll
        for (int j = 0; j < 4; ++j)
          // D layout (m89): col = lane&15, row = (lane>>4)*4 + j
          Ss[(mi * 16 + lk * 4 + j) * SS + wn * 32 + ni * 16 + lrow] = acc[mi][ni][j];
  }
  __syncthreads();
  if (wk == 0) {
#pragma unroll
    for (int mi = 0; mi < 4; ++mi)
#pragma unroll
      for (int ni = 0; ni < 2; ++ni)
#pragma unroll
        for (int j = 0; j < 4; ++j) {
          const int ixs = (mi * 16 + lk * 4 + j) * SS + wn * 32 + ni * 16 + lrow;
          Ss[ixs] += acc[mi][ni][j];
        }
  }
  __syncthreads();

  // ---- top-k epilogue: wave wid handles tokens wid, wid+8, ...
  const float bb0 = bias[lane];
  const float bb1 = bias[lane + 64];

  for (int t = wid; t < BM; t += 8) {
    const float lg0 = Ss[t * SS + lane];
    const float lg1 = Ss[t * SS + 64 + lane];
    const float s0 = 1.0f / (1.0f + expf(-lg0));  // raw sigmoid score
    const float s1 = 1.0f / (1.0f + expf(-lg1));
    float c0 = s0 + bb0;                          // bias-corrected, for selection
    float c1 = s1 + bb1;

    int   sel_i[TOPK];
    float sel_r[TOPK];
    float rsum = 0.0f;
#pragma unroll
    for (int j = 0; j < TOPK; ++j) {
      const bool take0 = (c0 >= c1);
      float v  = take0 ? c0 : c1;
      float rr = take0 ? s0 : s1;
      int   ii = take0 ? lane : lane + 64;
#pragma unroll
      for (int off = 32; off > 0; off >>= 1) {
        const float ov  = __shfl_xor(v, off, 64);
        const float orr = __shfl_xor(rr, off, 64);
        const int   oi  = __shfl_xor(ii, off, 64);
        if (ov > v || (ov == v && oi < ii)) { v = ov; rr = orr; ii = oi; }
      }
      sel_i[j] = ii;
      sel_r[j] = rr;
      rsum += rr;
      if (ii == lane)      c0 = -__builtin_inff();
      if (ii == lane + 64) c1 = -__builtin_inff();
    }
    if (lane == 0) {
      const float inv = 1.0f / (rsum + 1e-20f);
      const size_t tok = (size_t)(row0 + t);
#pragma unroll
      for (int j = 0; j < TOPK; ++j) {
        out[tok * TOPK + j]                    = (float)sel_i[j];
        out[(size_t)T * TOPK + tok * TOPK + j] = sel_r[j] * inv;
      }
    }
  }
}

extern "C" void kernel_launch(void* const* d_in, const int* in_sizes, int n_in,
                              void* d_out, int out_size, void* d_ws, size_t ws_size,
                              hipStream_t stream) {
  const float* h    = (const float*)d_in[0];
  const float* w    = (const float*)d_in[1];
  const float* bias = (const float*)d_in[2];
  float* out = (float*)d_out;
  ushort* wp = (ushort*)d_ws;          // needs 1024*1536*2 B = 3 MiB
  const int T = in_sizes[0] / HIDDEN;  // 16384

  hipLaunchKernelGGL(pack_w_kernel, dim3(256), dim3(256), 0, stream, w, wp);

  dim3 grid(T / BM);   // 256 blocks -> 1 per CU
  dim3 block(512);     // 8 waves: 4 expert tiles x 2 K-halves
  hipLaunchKernelGGL(router_kernel, grid, block, 0, stream, h, wp, bias, out, T);
}

// Round 6
// 442.557 us; speedup vs baseline: 1.1809x; 1.1809x over previous
//
#include <hip/hip_runtime.h>
#include <math.h>

#define HIDDEN 4096
#define NEXP   128
#define TOPK   8
#define BM     64
#define BKC    64                  // K per staged chunk (wave does its wk-half)
#define NCHUNK (HIDDEN / BKC)      // 64
#define SS     132                 // padded stride for score rows in epilogue

// LDS ushort layout, double-buffered (buf b at b*BUFU):
//   A plane s: base + s*4096     ([64 rows][64 k] bf16, XOR-swizzled 16B)
//   B frag f : base + BOFF + f*512  (f = ((wn*2+ni)*2+wk)*3+s, lane-linear)
// per buf = 12288 (A) + 24576 (B) = 36864 ushorts = 72 KB; dbuf = 144 KB.
// Epilogue Ss[64][SS] floats aliases buf0 (after full drain + barrier).
#define BUFU 36864
#define BOFF 12288
#define SMEM_USHORT (2 * BUFU)

typedef __attribute__((ext_vector_type(8))) short short8;  // 8 bf16 (4 VGPR)
typedef __attribute__((ext_vector_type(4))) float f32x4;   // MFMA accumulator

__device__ __forceinline__ unsigned pack2(unsigned a, unsigned b) {
  return (a >> 16) | (b & 0xFFFF0000u);  // lo = top16(a), hi = top16(b)
}

// Triple bf16 split: x = hi + mid + lo + O(2^-24 x). hi/mid round-half-away.
struct Split3 { uint4 h, m, l; };
__device__ __forceinline__ Split3 split8(float4 a, float4 b) {
  float x[8] = {a.x, a.y, a.z, a.w, b.x, b.y, b.z, b.w};
  unsigned h[8], m[8], l[8];
#pragma unroll
  for (int j = 0; j < 8; ++j) {
    unsigned u  = __float_as_uint(x[j]);
    unsigned hb = (u + 0x8000u) & 0xFFFF0000u;
    float rh    = x[j] - __uint_as_float(hb);
    unsigned um = __float_as_uint(rh);
    unsigned mb = (um + 0x8000u) & 0xFFFF0000u;
    float rm    = rh - __uint_as_float(mb);
    h[j] = hb; m[j] = mb; l[j] = __float_as_uint(rm);
  }
  Split3 s;
  s.h = make_uint4(pack2(h[0],h[1]), pack2(h[2],h[3]), pack2(h[4],h[5]), pack2(h[6],h[7]));
  s.m = make_uint4(pack2(m[0],m[1]), pack2(m[2],m[3]), pack2(m[4],m[5]), pack2(m[6],m[7]));
  s.l = make_uint4(pack2(l[0],l[1]), pack2(l[2],l[3]), pack2(l[4],l[5]), pack2(l[6],l[7]));
  return s;
}

// ---- pre-pass: split W into 3 bf16 planes, packed in MFMA B-fragment order.
// fid = et*128 + kc (et = 16-expert tile, kc = K/32 chunk).
// wp[fid*1536 + s*512 + lane*8 ..] = W_s[et*16 + (lane&15)][kc*32 + (lane>>4)*8 ..]
__global__ __launch_bounds__(256) void pack_w_kernel(
    const float* __restrict__ w, ushort* __restrict__ wp)
{
  const int g    = blockIdx.x * 256 + threadIdx.x;  // 65536 threads
  const int lane = g & 63;
  const int fid  = g >> 6;                          // 0..1023
  const int et   = fid >> 7;
  const int kc   = fid & 127;
  const int e    = et * 16 + (lane & 15);
  const int k0   = kc * 32 + (lane >> 4) * 8;
  const float4 x0 = *(const float4*)(w + (size_t)e * HIDDEN + k0);
  const float4 x1 = *(const float4*)(w + (size_t)e * HIDDEN + k0 + 4);
  Split3 s = split8(x0, x1);
  uint4* dst = (uint4*)wp + (size_t)fid * 3 * 64;
  dst[0 * 64 + lane] = s.h;
  dst[1 * 64 + lane] = s.m;
  dst[2 * 64 + lane] = s.l;
}

__device__ __forceinline__ void glds16(const ushort* g, ushort* l) {
  // async global->LDS, 16B/lane; LDS dest = wave-uniform base + lane*16
  __builtin_amdgcn_global_load_lds(
      (const __attribute__((address_space(1))) unsigned int*)g,
      (__attribute__((address_space(3))) unsigned int*)l, 16, 0, 0);
}

__global__ __launch_bounds__(512, 1) void router_kernel(
    const float*  __restrict__ h,     // [T, HIDDEN]
    const ushort* __restrict__ wp,    // packed split W (see pack_w_kernel)
    const float*  __restrict__ bias,  // [NEXP]
    float* __restrict__ out,          // [T*8] indices (as float) then [T*8] weights
    int T)
{
  __shared__ __align__(16) ushort smem_u[SMEM_USHORT];
  const int tid  = threadIdx.x;
  const int row0 = blockIdx.x * BM;

  const int wid  = tid >> 6;
  const int wn   = wid & 3;     // expert-column tile (32 experts)
  const int wk   = wid >> 2;    // K-parity half
  const int lane = tid & 63;
  const int lrow = lane & 15;
  const int lk   = lane >> 4;

  // A staging: thread owns 8 contiguous k of one token row
  const int sr = tid >> 3;      // row 0..63
  const int sk = tid & 7;       // 8-float group
  const float* gA = h + (size_t)(row0 + sr) * HIDDEN + sk * 8;
  const int six   = (sr * 64 + sk * 8) ^ ((sr & 7) << 3);

  // A fragment read offsets (swizzle uses lrow&7 since mi*16 keeps low 3 bits)
  int aix[4];
#pragma unroll
  for (int mi = 0; mi < 4; ++mi)
    aix[mi] = ((mi * 16 + lrow) * 64 + wk * 32 + lk * 8) ^ ((lrow & 7) << 3);

  // B LDS frag bases (wave-uniform) and read offsets
  int bB[2];
#pragma unroll
  for (int ni = 0; ni < 2; ++ni)
    bB[ni] = BOFF + ((wn * 2 + ni) * 2 + wk) * 3 * 512;

#define STAGE_B(ct, bb)                                                     \
  {                                                                         \
    _Pragma("unroll")                                                       \
    for (int ni_ = 0; ni_ < 2; ++ni_) {                                     \
      const ushort* src_ = wp                                               \
          + (size_t)((wn * 2 + ni_) * 128 + (ct) * 2 + wk) * 1536           \
          + (size_t)lane * 8;                                               \
      ushort* dst_ = smem_u + (bb) + bB[ni_];                               \
      _Pragma("unroll")                                                     \
      for (int s_ = 0; s_ < 3; ++s_)                                        \
        glds16(src_ + s_ * 512, dst_ + s_ * 512);                           \
    }                                                                       \
  }

  f32x4 acc[4][2];
#pragma unroll
  for (int i = 0; i < 4; ++i)
#pragma unroll
    for (int j = 0; j < 2; ++j) acc[i][j] = (f32x4){0.f, 0.f, 0.f, 0.f};

  // ---- prologue: A(0) staged, pa=A(1) and B(0) in flight (order: pa, then B)
  float4 pa0 = *(const float4*)(gA);
  float4 pa1 = *(const float4*)(gA + 4);
  {
    Split3 s = split8(pa0, pa1);        // compiler auto-waits vmcnt for pa
    *(uint4*)(smem_u + 0 * 4096 + six) = s.h;
    *(uint4*)(smem_u + 1 * 4096 + six) = s.m;
    *(uint4*)(smem_u + 2 * 4096 + six) = s.l;
  }
  pa0 = *(const float4*)(gA + BKC);
  pa1 = *(const float4*)(gA + BKC + 4);
  __builtin_amdgcn_sched_barrier(0);    // pin: pa issued before B gloads
  STAGE_B(0, 0)
  __builtin_amdgcn_sched_barrier(0);
  asm volatile("s_waitcnt lgkmcnt(0)" ::: "memory");
  __builtin_amdgcn_s_barrier();         // A(0) visible; vmcnt NOT drained

  // ---- main loop.  Steady-state in flight at barrier: pa(c+2)x2 + B(c+1)x6.
  for (int c = 0; c < NCHUNK; ++c) {
    const int cur = (c & 1) * BUFU;
    const int nxt = ((c + 1) & 1) * BUFU;

    // stage A(c+1) from pa (real dep -> compiler inserts counted vmcnt)
    {
      Split3 s = split8(pa0, pa1);
      *(uint4*)(smem_u + nxt + 0 * 4096 + six) = s.h;
      *(uint4*)(smem_u + nxt + 1 * 4096 + six) = s.m;
      *(uint4*)(smem_u + nxt + 2 * 4096 + six) = s.l;
    }
    // issue pa = A(c+2), then B(c+1) gloads (clamped; counts stay uniform)
    const int cA = (c + 2 < NCHUNK) ? c + 2 : NCHUNK - 1;
    pa0 = *(const float4*)(gA + cA * BKC);
    pa1 = *(const float4*)(gA + cA * BKC + 4);
    __builtin_amdgcn_sched_barrier(0);
    const int cB = (c + 1 < NCHUNK) ? c + 1 : NCHUNK - 1;
    STAGE_B(cB, nxt)
    __builtin_amdgcn_sched_barrier(0);
    // B(c) landed: 14 outstanding, wait oldest 6 (B(c)); keep pa+B(c+1)=8
    asm volatile("s_waitcnt vmcnt(8)" ::: "memory");

    // fragments from LDS
    short8 af[4][3];
#pragma unroll
    for (int mi = 0; mi < 4; ++mi) {
      af[mi][0] = *(const short8*)(smem_u + cur + 0 * 4096 + aix[mi]);
      af[mi][1] = *(const short8*)(smem_u + cur + 1 * 4096 + aix[mi]);
      af[mi][2] = *(const short8*)(smem_u + cur + 2 * 4096 + aix[mi]);
    }
    short8 bf[2][3];
#pragma unroll
    for (int ni = 0; ni < 2; ++ni)
#pragma unroll
      for (int s = 0; s < 3; ++s)
        bf[ni][s] = *(const short8*)(smem_u + cur + bB[ni] + s * 512 + lane * 8);

    __builtin_amdgcn_s_setprio(1);
#pragma unroll
    for (int mi = 0; mi < 4; ++mi)
#pragma unroll
      for (int ni = 0; ni < 2; ++ni) {
        f32x4 cc = acc[mi][ni];
        cc = __builtin_amdgcn_mfma_f32_16x16x32_bf16(af[mi][0], bf[ni][0], cc, 0, 0, 0);
        cc = __builtin_amdgcn_mfma_f32_16x16x32_bf16(af[mi][0], bf[ni][1], cc, 0, 0, 0);
        cc = __builtin_amdgcn_mfma_f32_16x16x32_bf16(af[mi][1], bf[ni][0], cc, 0, 0, 0);
        cc = __builtin_amdgcn_mfma_f32_16x16x32_bf16(af[mi][0], bf[ni][2], cc, 0, 0, 0);
        cc = __builtin_amdgcn_mfma_f32_16x16x32_bf16(af[mi][2], bf[ni][0], cc, 0, 0, 0);
        cc = __builtin_amdgcn_mfma_f32_16x16x32_bf16(af[mi][1], bf[ni][1], cc, 0, 0, 0);
        acc[mi][ni] = cc;
      }
    __builtin_amdgcn_s_setprio(0);

    // raw barrier: ds ops drained, global loads stay in flight (T3/T4)
    asm volatile("s_waitcnt lgkmcnt(0)" ::: "memory");
    __builtin_amdgcn_s_barrier();
  }
#undef STAGE_B

  // full drain before LDS is repurposed (in-flight gloads write buf regions)
  asm volatile("s_waitcnt vmcnt(0) lgkmcnt(0)" ::: "memory");
  __builtin_amdgcn_s_barrier();

  // ---- combine wave-pair K-partials into score buffer (aliases buf0)
  float* Ss = (float*)smem_u;   // [64][SS]
  if (wk == 1) {
#pragma unroll
    for (int mi = 0; mi < 4; ++mi)
#pragma unroll
      for (int ni = 0; ni < 2; ++ni)
#pragma unroll
        for (int j = 0; j < 4; ++j)
          // D layout (m89): col = lane&15, row = (lane>>4)*4 + j
          Ss[(mi * 16 + lk * 4 + j) * SS + wn * 32 + ni * 16 + lrow] = acc[mi][ni][j];
  }
  __syncthreads();
  if (wk == 0) {
#pragma unroll
    for (int mi = 0; mi < 4; ++mi)
#pragma unroll
      for (int ni = 0; ni < 2; ++ni)
#pragma unroll
        for (int j = 0; j < 4; ++j) {
          const int ixs = (mi * 16 + lk * 4 + j) * SS + wn * 32 + ni * 16 + lrow;
          Ss[ixs] += acc[mi][ni][j];
        }
  }
  __syncthreads();

  // ---- top-k epilogue: wave wid handles tokens wid, wid+8, ...
  const float bb0 = bias[lane];
  const float bb1 = bias[lane + 64];

  for (int t = wid; t < BM; t += 8) {
    const float lg0 = Ss[t * SS + lane];
    const float lg1 = Ss[t * SS + 64 + lane];
    const float s0 = 1.0f / (1.0f + expf(-lg0));  // raw sigmoid score
    const float s1 = 1.0f / (1.0f + expf(-lg1));
    float c0 = s0 + bb0;                          // bias-corrected, for selection
    float c1 = s1 + bb1;

    int   sel_i[TOPK];
    float sel_r[TOPK];
    float rsum = 0.0f;
#pragma unroll
    for (int j = 0; j < TOPK; ++j) {
      const bool take0 = (c0 >= c1);
      float v  = take0 ? c0 : c1;
      float rr = take0 ? s0 : s1;
      int   ii = take0 ? lane : lane + 64;
#pragma unroll
      for (int off = 32; off > 0; off >>= 1) {
        const float ov  = __shfl_xor(v, off, 64);
        const float orr = __shfl_xor(rr, off, 64);
        const int   oi  = __shfl_xor(ii, off, 64);
        if (ov > v || (ov == v && oi < ii)) { v = ov; rr = orr; ii = oi; }
      }
      sel_i[j] = ii;
      sel_r[j] = rr;
      rsum += rr;
      if (ii == lane)      c0 = -__builtin_inff();
      if (ii == lane + 64) c1 = -__builtin_inff();
    }
    if (lane == 0) {
      const float inv = 1.0f / (rsum + 1e-20f);
      const size_t tok = (size_t)(row0 + t);
#pragma unroll
      for (int j = 0; j < TOPK; ++j) {
        out[tok * TOPK + j]                    = (float)sel_i[j];
        out[(size_t)T * TOPK + tok * TOPK + j] = sel_r[j] * inv;
      }
    }
  }
}

extern "C" void kernel_launch(void* const* d_in, const int* in_sizes, int n_in,
                              void* d_out, int out_size, void* d_ws, size_t ws_size,
                              hipStream_t stream) {
  const float* h    = (const float*)d_in[0];
  const float* w    = (const float*)d_in[1];
  const float* bias = (const float*)d_in[2];
  float* out = (float*)d_out;
  ushort* wp = (ushort*)d_ws;          // needs 1024*1536*2 B = 3 MiB
  const int T = in_sizes[0] / HIDDEN;  // 16384

  hipLaunchKernelGGL(pack_w_kernel, dim3(256), dim3(256), 0, stream, w, wp);

  dim3 grid(T / BM);   // 256 blocks -> 1 per CU
  dim3 block(512);     // 8 waves: 4 expert tiles x 2 K-halves
  hipLaunchKernelGGL(router_kernel, grid, block, 0, stream, h, wp, bias, out, T);
}